// Round 4
// baseline (1303.813 us; speedup 1.0000x reference)
//
#include <hip/hip_runtime.h>
#include <math.h>

// Problem constants
constexpr int Bb = 64;    // batch
constexpr int Pp = 400;   // passage len
constexpr int Qq = 50;    // question len
constexpr int Ee = 300;   // embed dim
constexpr int Hh = 256;   // hidden
constexpr int H3 = 768;   // 3*H
constexpr int Dd = 512;   // 2*H

#define NEGC (-10000000.0f)
#define LOGTINY (-103.278929903f)   // log(float32(1e-45)) = log(2^-149)

typedef _Float16 h2 __attribute__((ext_vector_type(2)));
typedef _Float16 f16x8 __attribute__((ext_vector_type(8)));
typedef float f32x4 __attribute__((ext_vector_type(4)));

__device__ __forceinline__ float allred(float v){
  #pragma unroll
  for (int off = 1; off < 64; off <<= 1) v += __shfl_xor(v, off);
  return v;
}
__device__ __forceinline__ float allmax(float v){
  #pragma unroll
  for (int off = 1; off < 64; off <<= 1) v = fmaxf(v, __shfl_xor(v, off));
  return v;
}
__device__ __forceinline__ float sigm(float x){ return 1.f / (1.f + expf(-x)); }

__device__ __forceinline__ float dot2f(unsigned a, unsigned b, float c){
#if __has_builtin(__builtin_amdgcn_fdot2)
  return __builtin_amdgcn_fdot2(__builtin_bit_cast(h2, a), __builtin_bit_cast(h2, b), c, false);
#else
  float r = c;
  asm("v_dot2_f32_f16 %0, %1, %2, %0" : "+v"(r) : "v"(a), "s"(b));
  return r;
#endif
}

// ---------------------------------------------------------------------------
// Pack Whh to fp16 pairs, laid out so the GRU kernel's uint4 loads coalesce:
// w16[ (((g*2+d)*32 + q)*768 + j)*4 + c ] = pack(W[d][j][2p], W[d][j][2p+1]),
// with pair p = 4q + c.
// ---------------------------------------------------------------------------
__global__ __launch_bounds__(256) void prep_w16(const float* __restrict__ pW,
                                                const float* __restrict__ qW,
                                                unsigned* __restrict__ w16){
  int idx = blockIdx.x * 256 + threadIdx.x;   // pair id
  if (idx >= 2 * 2 * 128 * H3) return;
  int j = idx % H3; int r = idx / H3;
  int p = r % 128; r /= 128;
  int d = r & 1; int g = r >> 1;
  const float* W = g ? qW : pW;
  float w0 = W[((size_t)d * H3 + j) * Hh + 2 * p];
  float w1 = W[((size_t)d * H3 + j) * Hh + 2 * p + 1];
  _Float16 a = (_Float16)w0, b = (_Float16)w1;
  unsigned short ua, ub;
  __builtin_memcpy(&ua, &a, 2); __builtin_memcpy(&ub, &b, 2);
  unsigned out = (unsigned)ua | ((unsigned)ub << 16);
  w16[(((size_t)(g * 2 + d) * 32 + (p >> 2)) * H3 + j) * 4 + (p & 3)] = out;
}

// ---------------------------------------------------------------------------
// xproj via MFMA (fp16 in, fp32 acc): out[d][b][t][h] = emb[tok] @ Wih^T + b.
// ---------------------------------------------------------------------------
__global__ __launch_bounds__(512) void xproj_mfma(const int* __restrict__ tok,
                                                  const float* __restrict__ emb,
                                                  const float* __restrict__ Wih,
                                                  const float* __restrict__ bih,
                                                  float* __restrict__ xp, int T){
  __shared__ __align__(16) _Float16 As[128][72];
  __shared__ __align__(16) _Float16 Bs[128][72];
  int tid = threadIdx.x;
  int m0 = blockIdx.y * 128;
  int nt = blockIdx.x;                 // 0..11
  int d = nt / 6, h0 = (nt % 6) * 128;
  int wid = tid >> 6, lane = tid & 63;
  int wr = wid >> 2, wc = wid & 3;

  int srow = tid >> 2;                 // 0..127
  int scol = (tid & 3) * 16;           // 0,16,32,48
  const float* aRow = emb + (size_t)tok[m0 + srow] * Ee;
  const float* bRow = Wih + ((size_t)d * H3 + h0 + srow) * Ee;

  f32x4 acc[4][2] = {};

  for (int k0 = 0; k0 < 320; k0 += 64){
    #pragma unroll
    for (int half = 0; half < 2; ++half){
      int k = k0 + scol + half * 8;
      float4 va0, va1, vb0, vb1;
      if (k + 8 <= Ee){
        va0 = *(const float4*)(aRow + k); va1 = *(const float4*)(aRow + k + 4);
        vb0 = *(const float4*)(bRow + k); vb1 = *(const float4*)(bRow + k + 4);
      } else if (k + 4 <= Ee){
        va0 = *(const float4*)(aRow + k); va1 = make_float4(0.f, 0.f, 0.f, 0.f);
        vb0 = *(const float4*)(bRow + k); vb1 = make_float4(0.f, 0.f, 0.f, 0.f);
      } else {
        va0 = va1 = vb0 = vb1 = make_float4(0.f, 0.f, 0.f, 0.f);
      }
      f16x8 a8 = { (_Float16)va0.x, (_Float16)va0.y, (_Float16)va0.z, (_Float16)va0.w,
                   (_Float16)va1.x, (_Float16)va1.y, (_Float16)va1.z, (_Float16)va1.w };
      f16x8 b8 = { (_Float16)vb0.x, (_Float16)vb0.y, (_Float16)vb0.z, (_Float16)vb0.w,
                   (_Float16)vb1.x, (_Float16)vb1.y, (_Float16)vb1.z, (_Float16)vb1.w };
      *(f16x8*)&As[srow][scol + half * 8] = a8;
      *(f16x8*)&Bs[srow][scol + half * 8] = b8;
    }
    __syncthreads();
    #pragma unroll
    for (int kc = 0; kc < 2; ++kc){
      int kb = kc * 32 + (lane >> 4) * 8;
      f16x8 af[4], bf[2];
      #pragma unroll
      for (int i = 0; i < 4; ++i) af[i] = *(const f16x8*)&As[wr * 64 + i * 16 + (lane & 15)][kb];
      #pragma unroll
      for (int jn = 0; jn < 2; ++jn) bf[jn] = *(const f16x8*)&Bs[wc * 32 + jn * 16 + (lane & 15)][kb];
      #pragma unroll
      for (int i = 0; i < 4; ++i)
        #pragma unroll
        for (int jn = 0; jn < 2; ++jn)
          acc[i][jn] = __builtin_amdgcn_mfma_f32_16x16x32_f16(af[i], bf[jn], acc[i][jn], 0, 0, 0);
    }
    __syncthreads();
  }

  #pragma unroll
  for (int jn = 0; jn < 2; ++jn){
    int h = h0 + wc * 32 + jn * 16 + (lane & 15);
    float bv = bih[d * H3 + h];
    #pragma unroll
    for (int i = 0; i < 4; ++i){
      #pragma unroll
      for (int r = 0; r < 4; ++r){
        int m = m0 + wr * 64 + i * 16 + (lane >> 4) * 4 + r;
        int bI = m / T, tI = m - bI * T;
        xp[(((size_t)d * Bb + bI) * T + tI) * H3 + h] = acc[i][jn][r] + bv;
      }
    }
  }
}

// ---------------------------------------------------------------------------
// Register-resident GRU. One WG per (seq-kind, dir, batch): 256 WGs x 768 thr,
// 3 waves/EU (cap 170 VGPR). Thread j holds Whh row j as 128 packed fp16-pair
// VGPRs; an empty asm on each value after the load makes it asm-defined so
// LLVM CANNOT rematerialize/sink the loads into the step loop (r3 failure:
// VGPR_Count=76 showed the loads were re-streamed every step).
// ---------------------------------------------------------------------------
__global__ __launch_bounds__(768, 3) void gru_kernel(const int* __restrict__ ptok,
                                                     const int* __restrict__ qtok,
                                                     const float* __restrict__ xpp,
                                                     const float* __restrict__ xpq,
                                                     const unsigned* __restrict__ w16,
                                                     const float* __restrict__ pbhh,
                                                     const float* __restrict__ qbhh,
                                                     float* __restrict__ Hp,
                                                     float* __restrict__ Hq){
  int wg = blockIdx.x;
  bool isp = wg < 128;
  int lw = isp ? wg : wg - 128;
  int d = lw & 1, b = lw >> 1;
  int T = isp ? Pp : Qq;
  const int* tok = (isp ? ptok : qtok) + b * T;
  const float* xrow = (isp ? xpp : xpq) + ((size_t)d * Bb + b) * T * H3;
  int gd = (isp ? 0 : 2) + d;
  const float* bhh = (isp ? pbhh : qbhh) + d * H3;
  float* Hout = (isp ? Hp : Hq) + (size_t)b * T * Dd + d * Hh;

  __shared__ __align__(4) _Float16 hs16[Hh];
  __shared__ float us[2 * Hh];

  int j = threadIdx.x;
  unsigned w[128];
  {
    const uint4* wq = (const uint4*)w16 + (size_t)gd * 32 * H3;
    #pragma unroll
    for (int q = 0; q < 32; ++q){
      uint4 v = wq[q * H3 + j];
      w[4 * q + 0] = v.x; w[4 * q + 1] = v.y; w[4 * q + 2] = v.z; w[4 * q + 3] = v.w;
    }
  }
  // Force register residency: each w[i] becomes asm-defined -> cannot be
  // rematerialized from memory inside the step loop.
  #pragma unroll
  for (int i = 0; i < 128; ++i) asm volatile("" : "+v"(w[i]));

  float bh = bhh[j];
  float h_old = 0.f;
  if (j < Hh) hs16[j] = (_Float16)0.f;
  __syncthreads();

  int lane = j & 63;
  float pre = xrow[(size_t)(d ? (T - 1) : 0) * H3 + j];

  for (int s = 0; s < T; ++s){
    int t = d ? (T - 1 - s) : s;
    float xt = pre;
    if (s + 1 < T) pre = xrow[(size_t)(d ? (T - 2 - s) : (s + 1)) * H3 + j];

    unsigned vh0 = *(const unsigned*)&hs16[2 * lane];
    unsigned vh1 = *(const unsigned*)&hs16[128 + 2 * lane];

    float acc0 = bh, acc1 = 0.f;
    #pragma unroll
    for (int q = 0; q < 32; ++q){
      #define RL(p) ((unsigned)__builtin_amdgcn_readlane((int)(((p) < 64) ? vh0 : vh1), (p) & 63))
      acc0 = dot2f(w[4 * q + 0], RL(4 * q + 0), acc0);
      acc1 = dot2f(w[4 * q + 1], RL(4 * q + 1), acc1);
      acc0 = dot2f(w[4 * q + 2], RL(4 * q + 2), acc0);
      acc1 = dot2f(w[4 * q + 3], RL(4 * q + 3), acc1);
      #undef RL
    }
    float acc = acc0 + acc1;
    if (j < 2 * Hh) us[j] = xt + acc;
    __syncthreads();
    if (j >= 2 * Hh){
      int jj = j - 2 * Hh;
      float r = sigm(us[jj]);
      float z = sigm(us[Hh + jj]);
      float n = tanhf(xt + r * acc);
      float hnew = (1.f - z) * n + z * h_old;
      float m = (tok[t] != 0) ? 1.f : 0.f;
      float hm = m * hnew + (1.f - m) * h_old;
      h_old = hm;
      hs16[jj] = (_Float16)hm;
      Hout[(size_t)t * Dd + jj] = hm * m;
    }
    __syncthreads();
  }
}

// ---------------------------------------------------------------------------
// Attention + logits (unchanged)
// ---------------------------------------------------------------------------
__global__ __launch_bounds__(512) void attn_kernel(const float* __restrict__ Hp,
                                                   const float* __restrict__ Hq,
                                                   const int* __restrict__ ptok,
                                                   const int* __restrict__ qtok,
                                                   const float* __restrict__ start_w,
                                                   const float* __restrict__ sbp,
                                                   const float* __restrict__ end_w,
                                                   const float* __restrict__ ebp,
                                                   float* __restrict__ out){
  extern __shared__ __align__(16) float lds[];
  float* hqs = lds;               // 50*512
  float* s2s = hqs + Qq * Dd;     // 64
  float* qms = s2s + 64;          // 64
  float* scw = qms + 64;          // 8*64
  float* aw  = scw + 512;         // 8*64

  int b = blockIdx.y, pc = blockIdx.x;
  int tid = threadIdx.x, wid = tid >> 6, lane = tid & 63;
  float sb = sbp[0], eb = ebp[0];

  float w1r[8], w2r[8], w3r[8], e1r[8], e2r[8], e3r[8];
  #pragma unroll
  for (int i = 0; i < 8; ++i){
    int c = lane * 8 + i;
    w1r[i] = start_w[c]; w2r[i] = start_w[Dd + c]; w3r[i] = start_w[2 * Dd + c];
    e1r[i] = end_w[c];   e2r[i] = end_w[Dd + c];   e3r[i] = end_w[2 * Dd + c];
  }
  for (int idx = tid; idx < Qq * Dd; idx += 512) hqs[idx] = Hq[(size_t)b * Qq * Dd + idx];
  __syncthreads();

  for (int q = wid; q < Qq; q += 8){
    float part = 0.f;
    const float* hq = hqs + q * Dd + lane * 8;
    #pragma unroll
    for (int i = 0; i < 8; ++i) part += hq[i] * w2r[i];
    part = allred(part);
    if (lane == 0){
      s2s[q] = part;
      qms[q] = (qtok[b * Qq + q] != 0) ? 1.f : 0.f;
    }
  }
  __syncthreads();

  for (int p = pc * 100 + wid; p < pc * 100 + 100; p += 8){
    const float* hprow = Hp + ((size_t)b * Pp + p) * Dd + lane * 8;
    float4 hv0 = *(const float4*)hprow;
    float4 hv1 = *(const float4*)(hprow + 4);
    float hpc[8] = {hv0.x, hv0.y, hv0.z, hv0.w, hv1.x, hv1.y, hv1.z, hv1.w};
    float hw3[8], he3[8];
    float s1 = 0.f, ed = 0.f;
    #pragma unroll
    for (int i = 0; i < 8; ++i){
      hw3[i] = hpc[i] * w3r[i];
      he3[i] = hpc[i] * e3r[i];
      s1 += hpc[i] * w1r[i];
      ed += hpc[i] * e1r[i];
    }
    #pragma unroll
    for (int off = 1; off < 64; off <<= 1){
      s1 += __shfl_xor(s1, off);
      ed += __shfl_xor(ed, off);
    }
    for (int q = 0; q < Qq; ++q){
      const float4* hq4 = (const float4*)(hqs + q * Dd + lane * 8);
      float4 a0 = hq4[0], a1 = hq4[1];
      float dot = hw3[0] * a0.x + hw3[1] * a0.y + hw3[2] * a0.z + hw3[3] * a0.w
                + hw3[4] * a1.x + hw3[5] * a1.y + hw3[6] * a1.z + hw3[7] * a1.w;
      dot = allred(dot);
      if (lane == 0) scw[wid * 64 + q] = (s1 + s2s[q] + dot + sb) * qms[q];
    }
    float v = (lane < Qq) ? scw[wid * 64 + lane] : -1e30f;
    float M = allmax(v);
    float ev = (lane < Qq) ? expf(v - M) : 0.f;
    float S = allred(ev);
    float am = (lane < Qq) ? (ev / S) * qms[lane] : 0.f;
    float Sm = allred(am);
    float af = am / (Sm + 1e-13f);
    if (lane < Qq) aw[wid * 64 + lane] = af;
    float wv[8] = {0.f, 0.f, 0.f, 0.f, 0.f, 0.f, 0.f, 0.f};
    for (int q = 0; q < Qq; ++q){
      float aq = aw[wid * 64 + q];
      const float4* hq4 = (const float4*)(hqs + q * Dd + lane * 8);
      float4 a0 = hq4[0], a1 = hq4[1];
      wv[0] += aq * a0.x; wv[1] += aq * a0.y; wv[2] += aq * a0.z; wv[3] += aq * a0.w;
      wv[4] += aq * a1.x; wv[5] += aq * a1.y; wv[6] += aq * a1.z; wv[7] += aq * a1.w;
    }
    float acc2 = 0.f, acc3 = 0.f, acc4 = 0.f, acc5 = 0.f;
    #pragma unroll
    for (int i = 0; i < 8; ++i){
      acc2 += wv[i] * w2r[i];
      acc3 += hw3[i] * wv[i];
      acc4 += wv[i] * e2r[i];
      acc5 += he3[i] * wv[i];
    }
    #pragma unroll
    for (int off = 1; off < 64; off <<= 1){
      acc2 += __shfl_xor(acc2, off);
      acc3 += __shfl_xor(acc3, off);
      acc4 += __shfl_xor(acc4, off);
      acc5 += __shfl_xor(acc5, off);
    }
    if (lane == 0){
      bool pm = (ptok[b * Pp + p] != 0);
      out[(size_t)b * Pp + p]                   = pm ? (s1 + acc2 + acc3 + sb) : NEGC;
      out[(size_t)Bb * Pp + (size_t)b * Pp + p] = pm ? (ed + acc4 + acc5 + eb) : NEGC;
    }
  }
}

// ---------------------------------------------------------------------------
// log_softmax over p (unchanged)
// ---------------------------------------------------------------------------
__global__ __launch_bounds__(512) void lsm_kernel(const int* __restrict__ ptok,
                                                  float* __restrict__ out){
  int b = blockIdx.x >> 1, sel = blockIdx.x & 1;
  const float* lg = out + (size_t)sel * Bb * Pp + (size_t)b * Pp;
  float* o = out + (size_t)(2 + sel) * Bb * Pp + (size_t)b * Pp;
  int tid = threadIdx.x;
  __shared__ float red1[8];
  __shared__ float red2[8];
  float x = -1e30f;
  if (tid < Pp) x = lg[tid] + ((ptok[b * Pp + tid] != 0) ? 0.f : LOGTINY);
  float m = allmax(x);
  if ((tid & 63) == 0) red1[tid >> 6] = m;
  __syncthreads();
  float M = red1[0];
  #pragma unroll
  for (int i = 1; i < 8; ++i) M = fmaxf(M, red1[i]);
  float e = (tid < Pp) ? expf(x - M) : 0.f;
  float s = allred(e);
  if ((tid & 63) == 0) red2[tid >> 6] = s;
  __syncthreads();
  float S = 0.f;
  #pragma unroll
  for (int i = 0; i < 8; ++i) S += red2[i];
  if (tid < Pp) o[tid] = (x - M) - logf(S);
}

// ---------------------------------------------------------------------------
extern "C" void kernel_launch(void* const* d_in, const int* in_sizes, int n_in,
                              void* d_out, int out_size, void* d_ws, size_t ws_size,
                              hipStream_t stream){
  const int*   passage  = (const int*)d_in[0];
  const int*   question = (const int*)d_in[1];
  const float* emb      = (const float*)d_in[2];
  const float* pW_ih    = (const float*)d_in[3];
  const float* pW_hh    = (const float*)d_in[4];
  const float* pb_ih    = (const float*)d_in[5];
  const float* pb_hh    = (const float*)d_in[6];
  const float* qW_ih    = (const float*)d_in[7];
  const float* qW_hh    = (const float*)d_in[8];
  const float* qb_ih    = (const float*)d_in[9];
  const float* qb_hh    = (const float*)d_in[10];
  const float* start_w  = (const float*)d_in[11];
  const float* start_b  = (const float*)d_in[12];
  const float* end_w    = (const float*)d_in[13];
  const float* end_b    = (const float*)d_in[14];
  float* out = (float*)d_out;

  // workspace layout (float-sized units)
  float*    ws  = (float*)d_ws;
  unsigned* w16 = (unsigned*)ws;            //   393216 u32 : packed fp16 Whh
  float*    xpp = ws + 393216;              // 39321600 : [d][b][t][768]
  float*    xpq = ws + 39714816;            //  4915200
  float*    Hp  = ws + 44630016;            // 13107200 : [b][t][512]
  float*    Hq  = ws + 57737216;            //  1638400
  // total 59,375,616 floats = 237.5 MB

  hipLaunchKernelGGL(prep_w16, dim3(1536), dim3(256), 0, stream, pW_hh, qW_hh, w16);
  hipLaunchKernelGGL(xproj_mfma, dim3(12, 200), dim3(512), 0, stream,
                     passage, emb, pW_ih, pb_ih, xpp, Pp);
  hipLaunchKernelGGL(xproj_mfma, dim3(12, 25), dim3(512), 0, stream,
                     question, emb, qW_ih, qb_ih, xpq, Qq);
  hipLaunchKernelGGL(gru_kernel, dim3(256), dim3(768), 0, stream,
                     passage, question, xpp, xpq, w16, pb_hh, qb_hh, Hp, Hq);
  size_t attn_lds = (size_t)(Qq * Dd + 64 + 64 + 512 + 512) * sizeof(float);
  hipLaunchKernelGGL(attn_kernel, dim3(4, 64), dim3(512), attn_lds, stream,
                     Hp, Hq, passage, question, start_w, start_b, end_w, end_b, out);
  hipLaunchKernelGGL(lsm_kernel, dim3(128), dim3(512), 0, stream, passage, out);
}

// Round 5
// 1193.140 us; speedup vs baseline: 1.0928x; 1.0928x over previous
//
#include <hip/hip_runtime.h>
#include <math.h>

// Problem constants
constexpr int Bb = 64;    // batch
constexpr int Pp = 400;   // passage len
constexpr int Qq = 50;    // question len
constexpr int Ee = 300;   // embed dim
constexpr int Hh = 256;   // hidden
constexpr int H3 = 768;   // 3*H
constexpr int Dd = 512;   // 2*H

#define NEGC (-10000000.0f)
#define LOGTINY (-103.278929903f)   // log(float32(1e-45)) = log(2^-149)

typedef _Float16 h2 __attribute__((ext_vector_type(2)));
typedef _Float16 f16x8 __attribute__((ext_vector_type(8)));
typedef float f32x4 __attribute__((ext_vector_type(4)));

__device__ __forceinline__ float allred(float v){
  #pragma unroll
  for (int off = 1; off < 64; off <<= 1) v += __shfl_xor(v, off);
  return v;
}
__device__ __forceinline__ float allmax(float v){
  #pragma unroll
  for (int off = 1; off < 64; off <<= 1) v = fmaxf(v, __shfl_xor(v, off));
  return v;
}
__device__ __forceinline__ float sigm(float x){ return 1.f / (1.f + expf(-x)); }

__device__ __forceinline__ float dot2f(unsigned a, unsigned b, float c){
#if __has_builtin(__builtin_amdgcn_fdot2)
  return __builtin_amdgcn_fdot2(__builtin_bit_cast(h2, a), __builtin_bit_cast(h2, b), c, false);
#else
  float r = c;
  asm("v_dot2_f32_f16 %0, %1, %2, %0" : "+v"(r) : "v"(a), "v"(b));
  return r;
#endif
}

// ---------------------------------------------------------------------------
// Pack Whh to fp16 pairs for the owner-thread layout:
// u32 slot idx = ((gd*3 + gate)*32 + q)*1024 + j*4 + c  holds pair p=4q+c of
// row (gate*256 + j):  pack(W[d][row][2p], W[d][row][2p+1]).
// Thread j's uint4 load (gate,q) is then consecutive-j coalesced.
// ---------------------------------------------------------------------------
__global__ __launch_bounds__(256) void prep_w16(const float* __restrict__ pW,
                                                const float* __restrict__ qW,
                                                unsigned* __restrict__ w16){
  int idx = blockIdx.x * 256 + threadIdx.x;   // u32 slot
  if (idx >= 2 * 2 * 3 * 32 * 256 * 4) return;
  int c = idx & 3;
  int j = (idx >> 2) & 255;
  int q = (idx >> 10) & 31;
  int gg = idx >> 15;            // gd*3 + gate
  int gate = gg % 3, gd = gg / 3;
  int d = gd & 1, g = gd >> 1;
  const float* W = g ? qW : pW;
  int p = q * 4 + c;
  int row = gate * 256 + j;
  const float* src = W + ((size_t)d * H3 + row) * Hh + 2 * p;
  _Float16 a = (_Float16)src[0], b = (_Float16)src[1];
  unsigned short ua, ub;
  __builtin_memcpy(&ua, &a, 2); __builtin_memcpy(&ub, &b, 2);
  w16[idx] = (unsigned)ua | ((unsigned)ub << 16);
}

// ---------------------------------------------------------------------------
// xproj via MFMA (fp16 in, fp32 acc): out[d][b][t][h] = emb[tok] @ Wih^T + b.
// ---------------------------------------------------------------------------
__global__ __launch_bounds__(512) void xproj_mfma(const int* __restrict__ tok,
                                                  const float* __restrict__ emb,
                                                  const float* __restrict__ Wih,
                                                  const float* __restrict__ bih,
                                                  float* __restrict__ xp, int T){
  __shared__ __align__(16) _Float16 As[128][72];
  __shared__ __align__(16) _Float16 Bs[128][72];
  int tid = threadIdx.x;
  int m0 = blockIdx.y * 128;
  int nt = blockIdx.x;                 // 0..11
  int d = nt / 6, h0 = (nt % 6) * 128;
  int wid = tid >> 6, lane = tid & 63;
  int wr = wid >> 2, wc = wid & 3;

  int srow = tid >> 2;                 // 0..127
  int scol = (tid & 3) * 16;           // 0,16,32,48
  const float* aRow = emb + (size_t)tok[m0 + srow] * Ee;
  const float* bRow = Wih + ((size_t)d * H3 + h0 + srow) * Ee;

  f32x4 acc[4][2] = {};

  for (int k0 = 0; k0 < 320; k0 += 64){
    #pragma unroll
    for (int half = 0; half < 2; ++half){
      int k = k0 + scol + half * 8;
      float4 va0, va1, vb0, vb1;
      if (k + 8 <= Ee){
        va0 = *(const float4*)(aRow + k); va1 = *(const float4*)(aRow + k + 4);
        vb0 = *(const float4*)(bRow + k); vb1 = *(const float4*)(bRow + k + 4);
      } else if (k + 4 <= Ee){
        va0 = *(const float4*)(aRow + k); va1 = make_float4(0.f, 0.f, 0.f, 0.f);
        vb0 = *(const float4*)(bRow + k); vb1 = make_float4(0.f, 0.f, 0.f, 0.f);
      } else {
        va0 = va1 = vb0 = vb1 = make_float4(0.f, 0.f, 0.f, 0.f);
      }
      f16x8 a8 = { (_Float16)va0.x, (_Float16)va0.y, (_Float16)va0.z, (_Float16)va0.w,
                   (_Float16)va1.x, (_Float16)va1.y, (_Float16)va1.z, (_Float16)va1.w };
      f16x8 b8 = { (_Float16)vb0.x, (_Float16)vb0.y, (_Float16)vb0.z, (_Float16)vb0.w,
                   (_Float16)vb1.x, (_Float16)vb1.y, (_Float16)vb1.z, (_Float16)vb1.w };
      *(f16x8*)&As[srow][scol + half * 8] = a8;
      *(f16x8*)&Bs[srow][scol + half * 8] = b8;
    }
    __syncthreads();
    #pragma unroll
    for (int kc = 0; kc < 2; ++kc){
      int kb = kc * 32 + (lane >> 4) * 8;
      f16x8 af[4], bf[2];
      #pragma unroll
      for (int i = 0; i < 4; ++i) af[i] = *(const f16x8*)&As[wr * 64 + i * 16 + (lane & 15)][kb];
      #pragma unroll
      for (int jn = 0; jn < 2; ++jn) bf[jn] = *(const f16x8*)&Bs[wc * 32 + jn * 16 + (lane & 15)][kb];
      #pragma unroll
      for (int i = 0; i < 4; ++i)
        #pragma unroll
        for (int jn = 0; jn < 2; ++jn)
          acc[i][jn] = __builtin_amdgcn_mfma_f32_16x16x32_f16(af[i], bf[jn], acc[i][jn], 0, 0, 0);
    }
    __syncthreads();
  }

  #pragma unroll
  for (int jn = 0; jn < 2; ++jn){
    int h = h0 + wc * 32 + jn * 16 + (lane & 15);
    float bv = bih[d * H3 + h];
    #pragma unroll
    for (int i = 0; i < 4; ++i){
      #pragma unroll
      for (int r = 0; r < 4; ++r){
        int m = m0 + wr * 64 + i * 16 + (lane >> 4) * 4 + r;
        int bI = m / T, tI = m - bI * T;
        xp[(((size_t)d * Bb + bI) * T + tI) * H3 + h] = acc[i][jn][r] + bv;
      }
    }
  }
}

// ---------------------------------------------------------------------------
// Register-resident GRU, owner-thread form. 256 WGs x 256 threads,
// __launch_bounds__(256,1): 4 waves/WG = 1 wave/SIMD -> per-thread VGPR cap
// 512. Thread j owns hidden unit j: rows j / 256+j / 512+j of Whh as
// 3 x 128 packed fp16-pair VGPRs (384 regs). Gates are thread-local;
// only h is exchanged per step (double-buffered LDS, 1 barrier/step).
// ---------------------------------------------------------------------------
__global__ __launch_bounds__(256, 1) void gru_kernel(const int* __restrict__ ptok,
                                                     const int* __restrict__ qtok,
                                                     const float* __restrict__ xpp,
                                                     const float* __restrict__ xpq,
                                                     const unsigned* __restrict__ w16,
                                                     const float* __restrict__ pbhh,
                                                     const float* __restrict__ qbhh,
                                                     float* __restrict__ Hp,
                                                     float* __restrict__ Hq){
  int wg = blockIdx.x;
  bool isp = wg < 128;
  int lw = isp ? wg : wg - 128;
  int d = lw & 1, b = lw >> 1;
  int T = isp ? Pp : Qq;
  const int* tok = (isp ? ptok : qtok) + b * T;
  const float* xrow = (isp ? xpp : xpq) + ((size_t)d * Bb + b) * T * H3;
  int gd = (isp ? 0 : 2) + d;
  const float* bhh = (isp ? pbhh : qbhh) + d * H3;
  float* Hout = (isp ? Hp : Hq) + (size_t)b * T * Dd + d * Hh;

  __shared__ __align__(4) _Float16 hbuf[2][Hh];

  int j = threadIdx.x;        // 0..255 : owned hidden unit
  int lane = j & 63;

  unsigned w0[128], w1[128], w2[128];
  {
    const uint4* wq = (const uint4*)w16 + (size_t)gd * 3 * 32 * 256;
    #pragma unroll
    for (int q = 0; q < 32; ++q){
      uint4 v0 = wq[(0 * 32 + q) * 256 + j];
      uint4 v1 = wq[(1 * 32 + q) * 256 + j];
      uint4 v2 = wq[(2 * 32 + q) * 256 + j];
      w0[4 * q + 0] = v0.x; w0[4 * q + 1] = v0.y; w0[4 * q + 2] = v0.z; w0[4 * q + 3] = v0.w;
      w1[4 * q + 0] = v1.x; w1[4 * q + 1] = v1.y; w1[4 * q + 2] = v1.z; w1[4 * q + 3] = v1.w;
      w2[4 * q + 0] = v2.x; w2[4 * q + 1] = v2.y; w2[4 * q + 2] = v2.z; w2[4 * q + 3] = v2.w;
    }
  }
  #pragma unroll
  for (int i = 0; i < 128; ++i){
    asm volatile("" : "+v"(w0[i]));
    asm volatile("" : "+v"(w1[i]));
    asm volatile("" : "+v"(w2[i]));
  }

  float bh0 = bhh[j], bh1 = bhh[Hh + j], bh2 = bhh[2 * Hh + j];
  float h_old = 0.f;
  hbuf[1][j] = (_Float16)0.f;     // step 0 reads buf[1]
  __syncthreads();

  int t0 = d ? (T - 1) : 0;
  float pre0 = xrow[(size_t)t0 * H3 + j];
  float pre1 = xrow[(size_t)t0 * H3 + Hh + j];
  float pre2 = xrow[(size_t)t0 * H3 + 2 * Hh + j];

  for (int s = 0; s < T; ++s){
    int t = d ? (T - 1 - s) : s;
    float xt0 = pre0, xt1 = pre1, xt2 = pre2;
    if (s + 1 < T){
      int tn = d ? (T - 2 - s) : (s + 1);
      pre0 = xrow[(size_t)tn * H3 + j];
      pre1 = xrow[(size_t)tn * H3 + Hh + j];
      pre2 = xrow[(size_t)tn * H3 + 2 * Hh + j];
    }
    const unsigned* hb = (const unsigned*)hbuf[(s + 1) & 1];
    unsigned vh0 = hb[lane];        // pairs 0..63 across lanes
    unsigned vh1 = hb[64 + lane];   // pairs 64..127

    float a0 = bh0, a1 = bh1, a2 = bh2;
    #pragma unroll
    for (int p = 0; p < 128; ++p){
      unsigned hv = (unsigned)__builtin_amdgcn_readlane((int)(p < 64 ? vh0 : vh1), p & 63);
      a0 = dot2f(w0[p], hv, a0);
      a1 = dot2f(w1[p], hv, a1);
      a2 = dot2f(w2[p], hv, a2);
    }
    float r = sigm(xt0 + a0);
    float z = sigm(xt1 + a1);
    float n = tanhf(xt2 + r * a2);
    float hnew = (1.f - z) * n + z * h_old;
    float m = (tok[t] != 0) ? 1.f : 0.f;
    float hm = m * hnew + (1.f - m) * h_old;
    h_old = hm;
    hbuf[s & 1][j] = (_Float16)hm;
    Hout[(size_t)t * Dd + j] = hm * m;
    __syncthreads();
  }
}

// ---------------------------------------------------------------------------
// Attention + logits (unchanged)
// ---------------------------------------------------------------------------
__global__ __launch_bounds__(512) void attn_kernel(const float* __restrict__ Hp,
                                                   const float* __restrict__ Hq,
                                                   const int* __restrict__ ptok,
                                                   const int* __restrict__ qtok,
                                                   const float* __restrict__ start_w,
                                                   const float* __restrict__ sbp,
                                                   const float* __restrict__ end_w,
                                                   const float* __restrict__ ebp,
                                                   float* __restrict__ out){
  extern __shared__ __align__(16) float lds[];
  float* hqs = lds;               // 50*512
  float* s2s = hqs + Qq * Dd;     // 64
  float* qms = s2s + 64;          // 64
  float* scw = qms + 64;          // 8*64
  float* aw  = scw + 512;         // 8*64

  int b = blockIdx.y, pc = blockIdx.x;
  int tid = threadIdx.x, wid = tid >> 6, lane = tid & 63;
  float sb = sbp[0], eb = ebp[0];

  float w1r[8], w2r[8], w3r[8], e1r[8], e2r[8], e3r[8];
  #pragma unroll
  for (int i = 0; i < 8; ++i){
    int c = lane * 8 + i;
    w1r[i] = start_w[c]; w2r[i] = start_w[Dd + c]; w3r[i] = start_w[2 * Dd + c];
    e1r[i] = end_w[c];   e2r[i] = end_w[Dd + c];   e3r[i] = end_w[2 * Dd + c];
  }
  for (int idx = tid; idx < Qq * Dd; idx += 512) hqs[idx] = Hq[(size_t)b * Qq * Dd + idx];
  __syncthreads();

  for (int q = wid; q < Qq; q += 8){
    float part = 0.f;
    const float* hq = hqs + q * Dd + lane * 8;
    #pragma unroll
    for (int i = 0; i < 8; ++i) part += hq[i] * w2r[i];
    part = allred(part);
    if (lane == 0){
      s2s[q] = part;
      qms[q] = (qtok[b * Qq + q] != 0) ? 1.f : 0.f;
    }
  }
  __syncthreads();

  for (int p = pc * 100 + wid; p < pc * 100 + 100; p += 8){
    const float* hprow = Hp + ((size_t)b * Pp + p) * Dd + lane * 8;
    float4 hv0 = *(const float4*)hprow;
    float4 hv1 = *(const float4*)(hprow + 4);
    float hpc[8] = {hv0.x, hv0.y, hv0.z, hv0.w, hv1.x, hv1.y, hv1.z, hv1.w};
    float hw3[8], he3[8];
    float s1 = 0.f, ed = 0.f;
    #pragma unroll
    for (int i = 0; i < 8; ++i){
      hw3[i] = hpc[i] * w3r[i];
      he3[i] = hpc[i] * e3r[i];
      s1 += hpc[i] * w1r[i];
      ed += hpc[i] * e1r[i];
    }
    #pragma unroll
    for (int off = 1; off < 64; off <<= 1){
      s1 += __shfl_xor(s1, off);
      ed += __shfl_xor(ed, off);
    }
    for (int q = 0; q < Qq; ++q){
      const float4* hq4 = (const float4*)(hqs + q * Dd + lane * 8);
      float4 a0 = hq4[0], a1 = hq4[1];
      float dot = hw3[0] * a0.x + hw3[1] * a0.y + hw3[2] * a0.z + hw3[3] * a0.w
                + hw3[4] * a1.x + hw3[5] * a1.y + hw3[6] * a1.z + hw3[7] * a1.w;
      dot = allred(dot);
      if (lane == 0) scw[wid * 64 + q] = (s1 + s2s[q] + dot + sb) * qms[q];
    }
    float v = (lane < Qq) ? scw[wid * 64 + lane] : -1e30f;
    float M = allmax(v);
    float ev = (lane < Qq) ? expf(v - M) : 0.f;
    float S = allred(ev);
    float am = (lane < Qq) ? (ev / S) * qms[lane] : 0.f;
    float Sm = allred(am);
    float af = am / (Sm + 1e-13f);
    if (lane < Qq) aw[wid * 64 + lane] = af;
    float wv[8] = {0.f, 0.f, 0.f, 0.f, 0.f, 0.f, 0.f, 0.f};
    for (int q = 0; q < Qq; ++q){
      float aq = aw[wid * 64 + q];
      const float4* hq4 = (const float4*)(hqs + q * Dd + lane * 8);
      float4 a0 = hq4[0], a1 = hq4[1];
      wv[0] += aq * a0.x; wv[1] += aq * a0.y; wv[2] += aq * a0.z; wv[3] += aq * a0.w;
      wv[4] += aq * a1.x; wv[5] += aq * a1.y; wv[6] += aq * a1.z; wv[7] += aq * a1.w;
    }
    float acc2 = 0.f, acc3 = 0.f, acc4 = 0.f, acc5 = 0.f;
    #pragma unroll
    for (int i = 0; i < 8; ++i){
      acc2 += wv[i] * w2r[i];
      acc3 += hw3[i] * wv[i];
      acc4 += wv[i] * e2r[i];
      acc5 += he3[i] * wv[i];
    }
    #pragma unroll
    for (int off = 1; off < 64; off <<= 1){
      acc2 += __shfl_xor(acc2, off);
      acc3 += __shfl_xor(acc3, off);
      acc4 += __shfl_xor(acc4, off);
      acc5 += __shfl_xor(acc5, off);
    }
    if (lane == 0){
      bool pm = (ptok[b * Pp + p] != 0);
      out[(size_t)b * Pp + p]                   = pm ? (s1 + acc2 + acc3 + sb) : NEGC;
      out[(size_t)Bb * Pp + (size_t)b * Pp + p] = pm ? (ed + acc4 + acc5 + eb) : NEGC;
    }
  }
}

// ---------------------------------------------------------------------------
// log_softmax over p (unchanged)
// ---------------------------------------------------------------------------
__global__ __launch_bounds__(512) void lsm_kernel(const int* __restrict__ ptok,
                                                  float* __restrict__ out){
  int b = blockIdx.x >> 1, sel = blockIdx.x & 1;
  const float* lg = out + (size_t)sel * Bb * Pp + (size_t)b * Pp;
  float* o = out + (size_t)(2 + sel) * Bb * Pp + (size_t)b * Pp;
  int tid = threadIdx.x;
  __shared__ float red1[8];
  __shared__ float red2[8];
  float x = -1e30f;
  if (tid < Pp) x = lg[tid] + ((ptok[b * Pp + tid] != 0) ? 0.f : LOGTINY);
  float m = allmax(x);
  if ((tid & 63) == 0) red1[tid >> 6] = m;
  __syncthreads();
  float M = red1[0];
  #pragma unroll
  for (int i = 1; i < 8; ++i) M = fmaxf(M, red1[i]);
  float e = (tid < Pp) ? expf(x - M) : 0.f;
  float s = allred(e);
  if ((tid & 63) == 0) red2[tid >> 6] = s;
  __syncthreads();
  float S = 0.f;
  #pragma unroll
  for (int i = 0; i < 8; ++i) S += red2[i];
  if (tid < Pp) o[tid] = (x - M) - logf(S);
}

// ---------------------------------------------------------------------------
extern "C" void kernel_launch(void* const* d_in, const int* in_sizes, int n_in,
                              void* d_out, int out_size, void* d_ws, size_t ws_size,
                              hipStream_t stream){
  const int*   passage  = (const int*)d_in[0];
  const int*   question = (const int*)d_in[1];
  const float* emb      = (const float*)d_in[2];
  const float* pW_ih    = (const float*)d_in[3];
  const float* pW_hh    = (const float*)d_in[4];
  const float* pb_ih    = (const float*)d_in[5];
  const float* pb_hh    = (const float*)d_in[6];
  const float* qW_ih    = (const float*)d_in[7];
  const float* qW_hh    = (const float*)d_in[8];
  const float* qb_ih    = (const float*)d_in[9];
  const float* qb_hh    = (const float*)d_in[10];
  const float* start_w  = (const float*)d_in[11];
  const float* start_b  = (const float*)d_in[12];
  const float* end_w    = (const float*)d_in[13];
  const float* end_b    = (const float*)d_in[14];
  float* out = (float*)d_out;

  // workspace layout (float-sized units)
  float*    ws  = (float*)d_ws;
  unsigned* w16 = (unsigned*)ws;            //   393216 u32 : packed fp16 Whh
  float*    xpp = ws + 393216;              // 39321600 : [d][b][t][768]
  float*    xpq = ws + 39714816;            //  4915200
  float*    Hp  = ws + 44630016;            // 13107200 : [b][t][512]
  float*    Hq  = ws + 57737216;            //  1638400
  // total 59,375,616 floats = 237.5 MB

  hipLaunchKernelGGL(prep_w16, dim3(1536), dim3(256), 0, stream, pW_hh, qW_hh, w16);
  hipLaunchKernelGGL(xproj_mfma, dim3(12, 200), dim3(512), 0, stream,
                     passage, emb, pW_ih, pb_ih, xpp, Pp);
  hipLaunchKernelGGL(xproj_mfma, dim3(12, 25), dim3(512), 0, stream,
                     question, emb, qW_ih, qb_ih, xpq, Qq);
  hipLaunchKernelGGL(gru_kernel, dim3(256), dim3(256), 0, stream,
                     passage, question, xpp, xpq, w16, pb_hh, qb_hh, Hp, Hq);
  size_t attn_lds = (size_t)(Qq * Dd + 64 + 64 + 512 + 512) * sizeof(float);
  hipLaunchKernelGGL(attn_kernel, dim3(4, 64), dim3(512), attn_lds, stream,
                     Hp, Hq, passage, question, start_w, start_b, end_w, end_b, out);
  hipLaunchKernelGGL(lsm_kernel, dim3(128), dim3(512), 0, stream, passage, out);
}

// Round 6
// 999.942 us; speedup vs baseline: 1.3039x; 1.1932x over previous
//
#include <hip/hip_runtime.h>
#include <math.h>

// Problem constants
constexpr int Bb = 64;    // batch
constexpr int Pp = 400;   // passage len
constexpr int Qq = 50;    // question len
constexpr int Ee = 300;   // embed dim
constexpr int Hh = 256;   // hidden
constexpr int H3 = 768;   // 3*H
constexpr int Dd = 512;   // 2*H

#define NEGC (-10000000.0f)
#define LOGTINY (-103.278929903f)   // log(float32(1e-45)) = log(2^-149)

typedef _Float16 h2 __attribute__((ext_vector_type(2)));
typedef _Float16 f16x8 __attribute__((ext_vector_type(8)));
typedef float f32x4 __attribute__((ext_vector_type(4)));

__device__ __forceinline__ float allred(float v){
  #pragma unroll
  for (int off = 1; off < 64; off <<= 1) v += __shfl_xor(v, off);
  return v;
}
__device__ __forceinline__ float allmax(float v){
  #pragma unroll
  for (int off = 1; off < 64; off <<= 1) v = fmaxf(v, __shfl_xor(v, off));
  return v;
}
__device__ __forceinline__ float sigm(float x){ return 1.f / (1.f + expf(-x)); }

__device__ __forceinline__ float dot2f(unsigned a, unsigned b, float c){
#if __has_builtin(__builtin_amdgcn_fdot2)
  return __builtin_amdgcn_fdot2(__builtin_bit_cast(h2, a), __builtin_bit_cast(h2, b), c, false);
#else
  float r = c;
  asm("v_dot2_f32_f16 %0, %1, %2, %0" : "+v"(r) : "v"(a), "v"(b));
  return r;
#endif
}

// ---------------------------------------------------------------------------
// Pack Whh to fp16 pairs for the half-split owner-thread layout.
// u32 slot idx = ((gd*3 + gate)*16 + q)*2048 + t*4 + c, where thread
// t = half*256 + j owns pair p = half*64 + q*4 + c of row (gate*256 + j):
// value = pack(W[d][row][2p], W[d][row][2p+1]). uint4 loads coalesce in t.
// ---------------------------------------------------------------------------
__global__ __launch_bounds__(256) void prep_w16(const float* __restrict__ pW,
                                                const float* __restrict__ qW,
                                                unsigned* __restrict__ w16){
  int idx = blockIdx.x * 256 + threadIdx.x;   // u32 slot
  if (idx >= 2 * 2 * 3 * 16 * 512 * 4) return;
  int c = idx & 3;
  int t = (idx >> 2) & 511;
  int q = (idx >> 11) & 15;
  int gg = idx >> 15;            // gd*3 + gate
  int gate = gg % 3, gd = gg / 3;
  int d = gd & 1, g = gd >> 1;
  int j = t & 255, half = t >> 8;
  int p = half * 64 + q * 4 + c;
  int row = gate * 256 + j;
  const float* W = g ? qW : pW;
  const float* src = W + ((size_t)d * H3 + row) * Hh + 2 * p;
  _Float16 a = (_Float16)src[0], b = (_Float16)src[1];
  unsigned short ua, ub;
  __builtin_memcpy(&ua, &a, 2); __builtin_memcpy(&ub, &b, 2);
  w16[idx] = (unsigned)ua | ((unsigned)ub << 16);
}

// ---------------------------------------------------------------------------
// xproj via MFMA (fp16 in, fp32 acc): out[d][b][t][h] = emb[tok] @ Wih^T + b.
// ---------------------------------------------------------------------------
__global__ __launch_bounds__(512) void xproj_mfma(const int* __restrict__ tok,
                                                  const float* __restrict__ emb,
                                                  const float* __restrict__ Wih,
                                                  const float* __restrict__ bih,
                                                  float* __restrict__ xp, int T){
  __shared__ __align__(16) _Float16 As[128][72];
  __shared__ __align__(16) _Float16 Bs[128][72];
  int tid = threadIdx.x;
  int m0 = blockIdx.y * 128;
  int nt = blockIdx.x;                 // 0..11
  int d = nt / 6, h0 = (nt % 6) * 128;
  int wid = tid >> 6, lane = tid & 63;
  int wr = wid >> 2, wc = wid & 3;

  int srow = tid >> 2;                 // 0..127
  int scol = (tid & 3) * 16;           // 0,16,32,48
  const float* aRow = emb + (size_t)tok[m0 + srow] * Ee;
  const float* bRow = Wih + ((size_t)d * H3 + h0 + srow) * Ee;

  f32x4 acc[4][2] = {};

  for (int k0 = 0; k0 < 320; k0 += 64){
    #pragma unroll
    for (int half = 0; half < 2; ++half){
      int k = k0 + scol + half * 8;
      float4 va0, va1, vb0, vb1;
      if (k + 8 <= Ee){
        va0 = *(const float4*)(aRow + k); va1 = *(const float4*)(aRow + k + 4);
        vb0 = *(const float4*)(bRow + k); vb1 = *(const float4*)(bRow + k + 4);
      } else if (k + 4 <= Ee){
        va0 = *(const float4*)(aRow + k); va1 = make_float4(0.f, 0.f, 0.f, 0.f);
        vb0 = *(const float4*)(bRow + k); vb1 = make_float4(0.f, 0.f, 0.f, 0.f);
      } else {
        va0 = va1 = vb0 = vb1 = make_float4(0.f, 0.f, 0.f, 0.f);
      }
      f16x8 a8 = { (_Float16)va0.x, (_Float16)va0.y, (_Float16)va0.z, (_Float16)va0.w,
                   (_Float16)va1.x, (_Float16)va1.y, (_Float16)va1.z, (_Float16)va1.w };
      f16x8 b8 = { (_Float16)vb0.x, (_Float16)vb0.y, (_Float16)vb0.z, (_Float16)vb0.w,
                   (_Float16)vb1.x, (_Float16)vb1.y, (_Float16)vb1.z, (_Float16)vb1.w };
      *(f16x8*)&As[srow][scol + half * 8] = a8;
      *(f16x8*)&Bs[srow][scol + half * 8] = b8;
    }
    __syncthreads();
    #pragma unroll
    for (int kc = 0; kc < 2; ++kc){
      int kb = kc * 32 + (lane >> 4) * 8;
      f16x8 af[4], bf[2];
      #pragma unroll
      for (int i = 0; i < 4; ++i) af[i] = *(const f16x8*)&As[wr * 64 + i * 16 + (lane & 15)][kb];
      #pragma unroll
      for (int jn = 0; jn < 2; ++jn) bf[jn] = *(const f16x8*)&Bs[wc * 32 + jn * 16 + (lane & 15)][kb];
      #pragma unroll
      for (int i = 0; i < 4; ++i)
        #pragma unroll
        for (int jn = 0; jn < 2; ++jn)
          acc[i][jn] = __builtin_amdgcn_mfma_f32_16x16x32_f16(af[i], bf[jn], acc[i][jn], 0, 0, 0);
    }
    __syncthreads();
  }

  #pragma unroll
  for (int jn = 0; jn < 2; ++jn){
    int h = h0 + wc * 32 + jn * 16 + (lane & 15);
    float bv = bih[d * H3 + h];
    #pragma unroll
    for (int i = 0; i < 4; ++i){
      #pragma unroll
      for (int r = 0; r < 4; ++r){
        int m = m0 + wr * 64 + i * 16 + (lane >> 4) * 4 + r;
        int bI = m / T, tI = m - bI * T;
        xp[(((size_t)d * Bb + bI) * T + tI) * H3 + h] = acc[i][jn][r] + bv;
      }
    }
  }
}

// ---------------------------------------------------------------------------
// Register-resident GRU, half-split owner-thread form. 256 WGs x 512 threads.
// amdgpu_waves_per_eu(2,2) pins 2 waves/SIMD -> 256-VGPR budget/thread.
// Thread t = half*256 + j owns half of hidden unit j's three Whh rows:
// 3 gates x 64 fp16-pairs = 192 weight VGPRs (fits the 256 arch cap; r5's
// 384 could not). Waves 0-3 are half 0, waves 4-7 half 1, so h-broadcast is
// one readlane per pair and all branches are wave-uniform. Halves combine
// via 3 LDS partials; gates finalize on half-0 waves. 2 barriers/step.
// ---------------------------------------------------------------------------
__global__ __launch_bounds__(512) __attribute__((amdgpu_waves_per_eu(2, 2)))
void gru_kernel(const int* __restrict__ ptok,
                const int* __restrict__ qtok,
                const float* __restrict__ xpp,
                const float* __restrict__ xpq,
                const unsigned* __restrict__ w16,
                const float* __restrict__ pbhh,
                const float* __restrict__ qbhh,
                float* __restrict__ Hp,
                float* __restrict__ Hq){
  int wg = blockIdx.x;
  bool isp = wg < 128;
  int lw = isp ? wg : wg - 128;
  int d = lw & 1, b = lw >> 1;
  int T = isp ? Pp : Qq;
  const int* tok = (isp ? ptok : qtok) + b * T;
  const float* xrow = (isp ? xpp : xpq) + ((size_t)d * Bb + b) * T * H3;
  int gd = (isp ? 0 : 2) + d;
  const float* bhh = (isp ? pbhh : qbhh) + d * H3;
  float* Hout = (isp ? Hp : Hq) + (size_t)b * T * Dd + d * Hh;

  __shared__ unsigned hbuf[2][128];   // packed fp16 h pairs, double-buffered
  __shared__ float pa[Hh], pb[Hh], pn[Hh];

  int t = threadIdx.x;
  int j = t & 255, half = t >> 8, lane = t & 63;

  unsigned w0[64], w1[64], w2[64];
  {
    const uint4* wq = (const uint4*)w16 + (size_t)gd * 3 * 16 * 512;
    #pragma unroll
    for (int q = 0; q < 16; ++q){
      uint4 v0 = wq[(0 * 16 + q) * 512 + t];
      uint4 v1 = wq[(1 * 16 + q) * 512 + t];
      uint4 v2 = wq[(2 * 16 + q) * 512 + t];
      w0[4 * q + 0] = v0.x; w0[4 * q + 1] = v0.y; w0[4 * q + 2] = v0.z; w0[4 * q + 3] = v0.w;
      w1[4 * q + 0] = v1.x; w1[4 * q + 1] = v1.y; w1[4 * q + 2] = v1.z; w1[4 * q + 3] = v1.w;
      w2[4 * q + 0] = v2.x; w2[4 * q + 1] = v2.y; w2[4 * q + 2] = v2.z; w2[4 * q + 3] = v2.w;
    }
  }
  #pragma unroll
  for (int i = 0; i < 64; ++i){
    asm volatile("" : "+v"(w0[i]));
    asm volatile("" : "+v"(w1[i]));
    asm volatile("" : "+v"(w2[i]));
  }

  float bh0 = bhh[j], bh1 = bhh[Hh + j], bh2 = bhh[2 * Hh + j];
  float h_old = 0.f;
  if (t < 128) hbuf[1][t] = 0u;     // step 0 reads buf[1]
  __syncthreads();

  int t0 = d ? (T - 1) : 0;
  float pre0 = 0.f, pre1 = 0.f, pre2 = 0.f;
  if (half == 0){
    pre0 = xrow[(size_t)t0 * H3 + j];
    pre1 = xrow[(size_t)t0 * H3 + Hh + j];
    pre2 = xrow[(size_t)t0 * H3 + 2 * Hh + j];
  }

  for (int s = 0; s < T; ++s){
    int tt = d ? (T - 1 - s) : s;
    unsigned vh = hbuf[(s + 1) & 1][half * 64 + lane];
    float a0 = 0.f, a1 = 0.f, a2 = 0.f;
    #pragma unroll
    for (int p = 0; p < 64; ++p){
      unsigned hv = (unsigned)__builtin_amdgcn_readlane((int)vh, p);
      a0 = dot2f(w0[p], hv, a0);
      a1 = dot2f(w1[p], hv, a1);
      a2 = dot2f(w2[p], hv, a2);
    }
    if (half == 1){ pa[j] = a0; pb[j] = a1; pn[j] = a2; }
    __syncthreads();
    if (half == 0){
      float xt0 = pre0, xt1 = pre1, xt2 = pre2;
      if (s + 1 < T){
        int tn = d ? (T - 2 - s) : (s + 1);
        pre0 = xrow[(size_t)tn * H3 + j];
        pre1 = xrow[(size_t)tn * H3 + Hh + j];
        pre2 = xrow[(size_t)tn * H3 + 2 * Hh + j];
      }
      float g0 = a0 + pa[j] + bh0;
      float g1 = a1 + pb[j] + bh1;
      float g2 = a2 + pn[j] + bh2;
      float r = sigm(xt0 + g0);
      float z = sigm(xt1 + g1);
      float n = tanhf(xt2 + r * g2);
      float hnew = (1.f - z) * n + z * h_old;
      float m = (tok[tt] != 0) ? 1.f : 0.f;
      float hm = m * hnew + (1.f - m) * h_old;
      h_old = hm;
      ((_Float16*)hbuf[s & 1])[j] = (_Float16)hm;
      Hout[(size_t)tt * Dd + j] = hm * m;
    }
    __syncthreads();
  }
}

// ---------------------------------------------------------------------------
// Attention + logits (unchanged)
// ---------------------------------------------------------------------------
__global__ __launch_bounds__(512) void attn_kernel(const float* __restrict__ Hp,
                                                   const float* __restrict__ Hq,
                                                   const int* __restrict__ ptok,
                                                   const int* __restrict__ qtok,
                                                   const float* __restrict__ start_w,
                                                   const float* __restrict__ sbp,
                                                   const float* __restrict__ end_w,
                                                   const float* __restrict__ ebp,
                                                   float* __restrict__ out){
  extern __shared__ __align__(16) float lds[];
  float* hqs = lds;               // 50*512
  float* s2s = hqs + Qq * Dd;     // 64
  float* qms = s2s + 64;          // 64
  float* scw = qms + 64;          // 8*64
  float* aw  = scw + 512;         // 8*64

  int b = blockIdx.y, pc = blockIdx.x;
  int tid = threadIdx.x, wid = tid >> 6, lane = tid & 63;
  float sb = sbp[0], eb = ebp[0];

  float w1r[8], w2r[8], w3r[8], e1r[8], e2r[8], e3r[8];
  #pragma unroll
  for (int i = 0; i < 8; ++i){
    int c = lane * 8 + i;
    w1r[i] = start_w[c]; w2r[i] = start_w[Dd + c]; w3r[i] = start_w[2 * Dd + c];
    e1r[i] = end_w[c];   e2r[i] = end_w[Dd + c];   e3r[i] = end_w[2 * Dd + c];
  }
  for (int idx = tid; idx < Qq * Dd; idx += 512) hqs[idx] = Hq[(size_t)b * Qq * Dd + idx];
  __syncthreads();

  for (int q = wid; q < Qq; q += 8){
    float part = 0.f;
    const float* hq = hqs + q * Dd + lane * 8;
    #pragma unroll
    for (int i = 0; i < 8; ++i) part += hq[i] * w2r[i];
    part = allred(part);
    if (lane == 0){
      s2s[q] = part;
      qms[q] = (qtok[b * Qq + q] != 0) ? 1.f : 0.f;
    }
  }
  __syncthreads();

  for (int p = pc * 100 + wid; p < pc * 100 + 100; p += 8){
    const float* hprow = Hp + ((size_t)b * Pp + p) * Dd + lane * 8;
    float4 hv0 = *(const float4*)hprow;
    float4 hv1 = *(const float4*)(hprow + 4);
    float hpc[8] = {hv0.x, hv0.y, hv0.z, hv0.w, hv1.x, hv1.y, hv1.z, hv1.w};
    float hw3[8], he3[8];
    float s1 = 0.f, ed = 0.f;
    #pragma unroll
    for (int i = 0; i < 8; ++i){
      hw3[i] = hpc[i] * w3r[i];
      he3[i] = hpc[i] * e3r[i];
      s1 += hpc[i] * w1r[i];
      ed += hpc[i] * e1r[i];
    }
    #pragma unroll
    for (int off = 1; off < 64; off <<= 1){
      s1 += __shfl_xor(s1, off);
      ed += __shfl_xor(ed, off);
    }
    for (int q = 0; q < Qq; ++q){
      const float4* hq4 = (const float4*)(hqs + q * Dd + lane * 8);
      float4 a0 = hq4[0], a1 = hq4[1];
      float dot = hw3[0] * a0.x + hw3[1] * a0.y + hw3[2] * a0.z + hw3[3] * a0.w
                + hw3[4] * a1.x + hw3[5] * a1.y + hw3[6] * a1.z + hw3[7] * a1.w;
      dot = allred(dot);
      if (lane == 0) scw[wid * 64 + q] = (s1 + s2s[q] + dot + sb) * qms[q];
    }
    float v = (lane < Qq) ? scw[wid * 64 + lane] : -1e30f;
    float M = allmax(v);
    float ev = (lane < Qq) ? expf(v - M) : 0.f;
    float S = allred(ev);
    float am = (lane < Qq) ? (ev / S) * qms[lane] : 0.f;
    float Sm = allred(am);
    float af = am / (Sm + 1e-13f);
    if (lane < Qq) aw[wid * 64 + lane] = af;
    float wv[8] = {0.f, 0.f, 0.f, 0.f, 0.f, 0.f, 0.f, 0.f};
    for (int q = 0; q < Qq; ++q){
      float aq = aw[wid * 64 + q];
      const float4* hq4 = (const float4*)(hqs + q * Dd + lane * 8);
      float4 a0 = hq4[0], a1 = hq4[1];
      wv[0] += aq * a0.x; wv[1] += aq * a0.y; wv[2] += aq * a0.z; wv[3] += aq * a0.w;
      wv[4] += aq * a1.x; wv[5] += aq * a1.y; wv[6] += aq * a1.z; wv[7] += aq * a1.w;
    }
    float acc2 = 0.f, acc3 = 0.f, acc4 = 0.f, acc5 = 0.f;
    #pragma unroll
    for (int i = 0; i < 8; ++i){
      acc2 += wv[i] * w2r[i];
      acc3 += hw3[i] * wv[i];
      acc4 += wv[i] * e2r[i];
      acc5 += he3[i] * wv[i];
    }
    #pragma unroll
    for (int off = 1; off < 64; off <<= 1){
      acc2 += __shfl_xor(acc2, off);
      acc3 += __shfl_xor(acc3, off);
      acc4 += __shfl_xor(acc4, off);
      acc5 += __shfl_xor(acc5, off);
    }
    if (lane == 0){
      bool pm = (ptok[b * Pp + p] != 0);
      out[(size_t)b * Pp + p]                   = pm ? (s1 + acc2 + acc3 + sb) : NEGC;
      out[(size_t)Bb * Pp + (size_t)b * Pp + p] = pm ? (ed + acc4 + acc5 + eb) : NEGC;
    }
  }
}

// ---------------------------------------------------------------------------
// log_softmax over p (unchanged)
// ---------------------------------------------------------------------------
__global__ __launch_bounds__(512) void lsm_kernel(const int* __restrict__ ptok,
                                                  float* __restrict__ out){
  int b = blockIdx.x >> 1, sel = blockIdx.x & 1;
  const float* lg = out + (size_t)sel * Bb * Pp + (size_t)b * Pp;
  float* o = out + (size_t)(2 + sel) * Bb * Pp + (size_t)b * Pp;
  int tid = threadIdx.x;
  __shared__ float red1[8];
  __shared__ float red2[8];
  float x = -1e30f;
  if (tid < Pp) x = lg[tid] + ((ptok[b * Pp + tid] != 0) ? 0.f : LOGTINY);
  float m = allmax(x);
  if ((tid & 63) == 0) red1[tid >> 6] = m;
  __syncthreads();
  float M = red1[0];
  #pragma unroll
  for (int i = 1; i < 8; ++i) M = fmaxf(M, red1[i]);
  float e = (tid < Pp) ? expf(x - M) : 0.f;
  float s = allred(e);
  if ((tid & 63) == 0) red2[tid >> 6] = s;
  __syncthreads();
  float S = 0.f;
  #pragma unroll
  for (int i = 0; i < 8; ++i) S += red2[i];
  if (tid < Pp) o[tid] = (x - M) - logf(S);
}

// ---------------------------------------------------------------------------
extern "C" void kernel_launch(void* const* d_in, const int* in_sizes, int n_in,
                              void* d_out, int out_size, void* d_ws, size_t ws_size,
                              hipStream_t stream){
  const int*   passage  = (const int*)d_in[0];
  const int*   question = (const int*)d_in[1];
  const float* emb      = (const float*)d_in[2];
  const float* pW_ih    = (const float*)d_in[3];
  const float* pW_hh    = (const float*)d_in[4];
  const float* pb_ih    = (const float*)d_in[5];
  const float* pb_hh    = (const float*)d_in[6];
  const float* qW_ih    = (const float*)d_in[7];
  const float* qW_hh    = (const float*)d_in[8];
  const float* qb_ih    = (const float*)d_in[9];
  const float* qb_hh    = (const float*)d_in[10];
  const float* start_w  = (const float*)d_in[11];
  const float* start_b  = (const float*)d_in[12];
  const float* end_w    = (const float*)d_in[13];
  const float* end_b    = (const float*)d_in[14];
  float* out = (float*)d_out;

  // workspace layout (float-sized units)
  float*    ws  = (float*)d_ws;
  unsigned* w16 = (unsigned*)ws;            //   393216 u32 : packed fp16 Whh
  float*    xpp = ws + 393216;              // 39321600 : [d][b][t][768]
  float*    xpq = ws + 39714816;            //  4915200
  float*    Hp  = ws + 44630016;            // 13107200 : [b][t][512]
  float*    Hq  = ws + 57737216;            //  1638400
  // total 59,375,616 floats = 237.5 MB

  hipLaunchKernelGGL(prep_w16, dim3(1536), dim3(256), 0, stream, pW_hh, qW_hh, w16);
  hipLaunchKernelGGL(xproj_mfma, dim3(12, 200), dim3(512), 0, stream,
                     passage, emb, pW_ih, pb_ih, xpp, Pp);
  hipLaunchKernelGGL(xproj_mfma, dim3(12, 25), dim3(512), 0, stream,
                     question, emb, qW_ih, qb_ih, xpq, Qq);
  hipLaunchKernelGGL(gru_kernel, dim3(256), dim3(512), 0, stream,
                     passage, question, xpp, xpq, w16, pb_hh, qb_hh, Hp, Hq);
  size_t attn_lds = (size_t)(Qq * Dd + 64 + 64 + 512 + 512) * sizeof(float);
  hipLaunchKernelGGL(attn_kernel, dim3(4, 64), dim3(512), attn_lds, stream,
                     Hp, Hq, passage, question, start_w, start_b, end_w, end_b, out);
  hipLaunchKernelGGL(lsm_kernel, dim3(128), dim3(512), 0, stream, passage, out);
}